// Round 4
// baseline (592.186 us; speedup 1.0000x reference)
//
#include <hip/hip_runtime.h>

// HashEncoder forward, R7 (= R6 with nontemporal-builtin type fix).
// R5 post-mortem: VGPR stayed 32 => compiler serialized the 2-point gather
// batches; per-wave MLP never increased (experiment was void). R6/R7 force it:
//  - __launch_bounds__(256, 8): VGPR cap 64 (8 waves/SIMD maintained; 33..64
//    VGPRs are occupancy-free), compiler can keep 16 gathers in flight.
//  - compact per-point state (fx/fy/fz + packed lo/odd meta) ~56 VGPRs.
//  - asm "memory" barrier between issue phase and consume phase pins all
//    gather issues before the first dependent waitcnt.
//  - nt stores for stage (streaming 134MB no longer evicts L2-resident table).
//    NOTE: __builtin_nontemporal_* requires native clang vector types, not
//    HIP_vector_type (float4/float2) — use ext_vector_type shims.
// Structure otherwise = R3/R5 3-pass (per-level dispatch is load-bearing for
// per-XCD L2 table locality; R4 proved fusion costs 9x FETCH).

static constexpr uint32_t P1 = 2654435761u;
static constexpr uint32_t P2 = 805459861u;
static constexpr uint32_t NPARAMS = 7114752u;
static constexpr uint32_t HMASK = 524287u;

typedef float f32x4 __attribute__((ext_vector_type(4)));
typedef float f32x2 __attribute__((ext_vector_type(2)));

// ---------- pass 0 ----------
__device__ inline uint32_t bf16_bits(float f) {
    uint32_t u = __float_as_uint(f);
    return (u + 0x7FFFu + ((u >> 16) & 1u)) >> 16;
}

__global__ __launch_bounds__(256) void convert_bf16(
    const float* __restrict__ emb, uint32_t* __restrict__ tab)
{
    const uint32_t i = blockIdx.x * 256u + threadIdx.x;   // float4 index
    const float4 v = ((const float4*)emb)[i];
    uint2 o;
    o.x = bf16_bits(v.x) | (bf16_bits(v.y) << 16);
    o.y = bf16_bits(v.z) | (bf16_bits(v.w) << 16);
    ((uint2*)tab)[i] = o;
}

// ---------- pass 1: 2 points x 1 level per thread, deep-MLP ----------
__global__ __launch_bounds__(256, 8) void enc_level2(
    const float* __restrict__ inp,
    const uint32_t* __restrict__ tab,   // packed bf16x2 per row
    float2* __restrict__ stage,         // [16][np]
    int npoints)
{
    const uint32_t l = blockIdx.y;
    const uint32_t u = blockIdx.x * 256u + threadIdx.x;   // point-pair index

    // input: 3x float2 covering points 2u, 2u+1 (24B, 8B-aligned)
    const float2* in2 = (const float2*)inp;
    const float2 ab = in2[3u * u + 0u];   // x0 y0
    const float2 cd = in2[3u * u + 1u];   // z0 x1
    const float2 ef = in2[3u * u + 2u];   // y1 z1

    const uint32_t res = 16u << l;
    const float scale = (float)(res - 1u);

    uint32_t off;
    if (l >= 3u)      off = 299008u + (l - 3u) * 524288u;
    else if (l == 2u) off = 36864u;
    else if (l == 1u) off = 4096u;
    else              off = 0u;
    const bool hashed = (l >= 3u);
    const uint32_t s = 4u + (hashed ? 0u : l);

    const float xs[2] = {ab.x, cd.y};
    const float ys[2] = {ab.y, ef.x};
    const float zs[2] = {cd.x, ef.y};

    // persistent per-point state (kept minimal: 8+4+3+1 = 16 regs/point)
    uint2     pr[2][4];
    uint32_t  vBo[2][4];
    float     fxq[2], fyq[2], fzq[2];
    uint32_t  meta[2];   // bits0-3: idxA[c]&1, bit4: gx odd

    // ---- issue phase: all 16 gathers of both points before any consume ----
#pragma unroll
    for (int q = 0; q < 2; ++q) {
        const float posx = (xs[q] + 1.0f) * 0.5f * scale + 0.5f;
        const float posy = (ys[q] + 1.0f) * 0.5f * scale + 0.5f;
        const float posz = (zs[q] + 1.0f) * 0.5f * scale + 0.5f;
        const float fgx = floorf(posx), fgy = floorf(posy), fgz = floorf(posz);
        fxq[q] = posx - fgx; fyq[q] = posy - fgy; fzq[q] = posz - fgz;
        const uint32_t gx = (uint32_t)fgx, gy = (uint32_t)fgy, gz = (uint32_t)fgz;

        uint32_t yzc[4];
        if (hashed) {
            const uint32_t hy0 = gy * P1, hy1 = hy0 + P1;
            const uint32_t hz0 = gz * P2, hz1 = hz0 + P2;
            yzc[0] = hy0 ^ hz0; yzc[1] = hy1 ^ hz0;
            yzc[2] = hy0 ^ hz1; yzc[3] = hy1 ^ hz1;
        } else {
            const uint32_t dy0 = gy << s, dy1 = dy0 + (1u << s);
            const uint32_t dz0 = gz << (2u * s), dz1 = dz0 + (1u << (2u * s));
            yzc[0] = dy0 + dz0; yzc[1] = dy1 + dz0;
            yzc[2] = dy0 + dz1; yzc[3] = dy1 + dz1;
        }

        uint32_t ia[4];
#pragma unroll
        for (int c = 0; c < 4; ++c)
            ia[c] = hashed ? ((gx ^ yzc[c]) & HMASK) : (gx + yzc[c]);

        meta[q] = (ia[0] & 1u) | ((ia[1] & 1u) << 1) |
                  ((ia[2] & 1u) << 2) | ((ia[3] & 1u) << 3) |
                  ((gx & 1u) << 4);

        // 4 aligned 8B pair loads (cover both x-corners when gx even)
#pragma unroll
        for (int c = 0; c < 4; ++c)
            pr[q][c] = *(const uint2*)(tab + off + (ia[c] & ~1u));

        // odd-gx extra 4B loads, exec-masked
        if (gx & 1u) {
#pragma unroll
            for (int c = 0; c < 4; ++c) {
                const uint32_t idxB = hashed
                    ? (((gx + 1u) ^ yzc[c]) & HMASK)
                    : (ia[c] + 1u);
                vBo[q][c] = tab[off + idxB];
            }
        }
    }

    // pin: every gather above is issued before any dependent use below
    asm volatile("" ::: "memory");

    // ---- consume phase ----
    f32x4 r;
#pragma unroll
    for (int q = 0; q < 2; ++q) {
        const float wx0 = 1.0f - fxq[q], wx1 = fxq[q];
        const float wy[2] = {1.0f - fyq[q], fyq[q]};
        const float wz[2] = {1.0f - fzq[q], fzq[q]};
        const bool odd = (meta[q] & 16u) != 0u;
        float sx = 0.0f, sy = 0.0f;
#pragma unroll
        for (int c = 0; c < 4; ++c) {
            const uint32_t lo = (meta[q] >> c) & 1u;
            const uint32_t vA  = lo ? pr[q][c].y : pr[q][c].x;
            const uint32_t vBe = lo ? pr[q][c].x : pr[q][c].y;  // idxA^1, valid iff gx even
            const uint32_t vB  = odd ? vBo[q][c] : vBe;
            const float wyz = wy[c & 1] * wz[c >> 1];
            const float eAx = __uint_as_float(vA << 16);
            const float eAy = __uint_as_float(vA & 0xFFFF0000u);
            const float eBx = __uint_as_float(vB << 16);
            const float eBy = __uint_as_float(vB & 0xFFFF0000u);
            sx = fmaf(wyz, fmaf(wx0, eAx, wx1 * eBx), sx);
            sy = fmaf(wyz, fmaf(wx0, eAy, wx1 * eBy), sy);
        }
        r[2 * q + 0] = sx;
        r[2 * q + 1] = sy;
    }

    // one nt float4 store: stage[l][2u .. 2u+1] (streaming; don't evict table)
    __builtin_nontemporal_store(r,
        (f32x4*)&((float4*)stage)[(size_t)l * ((uint32_t)npoints >> 1) + u]);
}

// ---------- pass 2: LDS-tiled transpose ----------
__global__ __launch_bounds__(256) void transpose_out(
    const float2* __restrict__ stage, float4* __restrict__ out4, int npoints)
{
    __shared__ float2 t[256][17];   // +1 pad: 2 lanes/bank on load phase (free)
    const uint32_t p0 = blockIdx.x * 256u;
    const uint32_t tid = threadIdx.x;

#pragma unroll
    for (int l = 0; l < 16; ++l) {
        const f32x2 v = __builtin_nontemporal_load(
            (const f32x2*)&stage[(size_t)l * (uint32_t)npoints + p0 + tid]);  // coalesced 2KB
        t[tid][l] = make_float2(v.x, v.y);
    }
    __syncthreads();

#pragma unroll
    for (int k = 0; k < 8; ++k) {
        const uint32_t f = (uint32_t)k * 256u + tid;
        const uint32_t p = f >> 3, c = f & 7u;
        const float2 a = t[p][2u * c];
        const float2 b = t[p][2u * c + 1u];
        const f32x4 v = {a.x, a.y, b.x, b.y};
        __builtin_nontemporal_store(v,
            (f32x4*)&out4[(size_t)(p0 + p) * 8u + c]);                        // coalesced 4KB
    }
}

// ---------- fallback: single-pass (R1) ----------
__global__ __launch_bounds__(256) void hashenc_fwd(
    const float* __restrict__ inp, const float* __restrict__ emb,
    float* __restrict__ out, int npoints)
{
    const uint32_t tid = blockIdx.x * 256u + threadIdx.x;
    const uint32_t p = tid >> 4, l = tid & 15u;
    if (p >= (uint32_t)npoints) return;
    const float x01 = (inp[p * 3u + 0u] + 1.0f) * 0.5f;
    const float y01 = (inp[p * 3u + 1u] + 1.0f) * 0.5f;
    const float z01 = (inp[p * 3u + 2u] + 1.0f) * 0.5f;
    const uint32_t res = 16u << l;
    const float scale = (float)(res - 1u);
    const float posx = x01 * scale + 0.5f, posy = y01 * scale + 0.5f, posz = z01 * scale + 0.5f;
    const float fgx = floorf(posx), fgy = floorf(posy), fgz = floorf(posz);
    const float fx = posx - fgx, fy = posy - fgy, fz = posz - fgz;
    const uint32_t gx = (uint32_t)fgx, gy = (uint32_t)fgy, gz = (uint32_t)fgz;
    uint32_t off;
    if (l >= 3u)      off = 299008u + (l - 3u) * 524288u;
    else if (l == 2u) off = 36864u;
    else if (l == 1u) off = 4096u;
    else              off = 0u;
    const bool hashed = (l >= 3u);
    const uint32_t s = 4u + (hashed ? 0u : l);
    const float wx[2] = {1.0f - fx, fx}, wy[2] = {1.0f - fy, fy}, wz[2] = {1.0f - fz, fz};
    float2 g[8]; float w[8];
#pragma unroll
    for (int c = 0; c < 8; ++c) {
        const uint32_t bx = (uint32_t)c & 1u, by = ((uint32_t)c >> 1) & 1u, bz = ((uint32_t)c >> 2) & 1u;
        const uint32_t cx = gx + bx, cy = gy + by, cz = gz + bz;
        const uint32_t hidx = (cx ^ (cy * P1) ^ (cz * P2)) & HMASK;
        const uint32_t didx = cx + (cy << s) + (cz << (2u * s));
        const uint32_t idx  = hashed ? hidx : didx;
        w[c] = wx[bx] * wy[by] * wz[bz];
        g[c] = *(const float2*)(emb + 2u * (off + idx));
    }
    float sx = 0.0f, sy = 0.0f;
#pragma unroll
    for (int c = 0; c < 8; ++c) { sx = fmaf(w[c], g[c].x, sx); sy = fmaf(w[c], g[c].y, sy); }
    *(float2*)(out + (size_t)p * 32u + (size_t)l * 2u) = make_float2(sx, sy);
}

extern "C" void kernel_launch(void* const* d_in, const int* in_sizes, int n_in,
                              void* d_out, int out_size, void* d_ws, size_t ws_size,
                              hipStream_t stream) {
    const float* inp = (const float*)d_in[0];
    const float* emb = (const float*)d_in[1];
    float* out = (float*)d_out;
    const int npoints = in_sizes[0] / 3;

    const size_t tab_bytes = (size_t)NPARAMS * 4u;
    const size_t stage_bytes = (size_t)npoints * 16u * 8u;
    const size_t need = tab_bytes + stage_bytes;

    if (ws_size >= need && (npoints & 511) == 0) {
        uint32_t* tab = (uint32_t*)d_ws;
        float2* stage = (float2*)((char*)d_ws + tab_bytes);

        const int conv_units = (int)(NPARAMS * 2u / 4u);
        convert_bf16<<<(conv_units + 255) / 256, 256, 0, stream>>>(emb, tab);

        dim3 g1(npoints / 512, 16);
        enc_level2<<<g1, 256, 0, stream>>>(inp, tab, stage, npoints);

        transpose_out<<<npoints / 256, 256, 0, stream>>>(stage, (float4*)out, npoints);
    } else {
        const int total = npoints * 16;
        hashenc_fwd<<<(total + 255) / 256, 256, 0, stream>>>(inp, emb, out, npoints);
    }
}

// Round 5
// 586.433 us; speedup vs baseline: 1.0098x; 1.0098x over previous
//
#include <hip/hip_runtime.h>

// HashEncoder forward, R8.
// R5/R7 post-mortem: VGPR stuck at 32 — the compiler serialized the gather
// batches both times; per-wave MLP never rose, so H1 (latency-bound) vs H2
// (per-CU gather-line service cap ~0.5 lines/cy) is still untested.
// R8 makes MLP compiler-proof:
//  - every table gather is an asm volatile global_load_dword/x2 with "=v"
//    output + SGPR-pair base (saddr form, 32-bit byte voffset in 1 VGPR).
//    Volatile asm is mutually ordered; outputs pin distinct VGPRs => all 16
//    gathers of both points are in flight simultaneously.
//  - manual s_waitcnt vmcnt(0) + sched_barrier(0) before consume (rule #18:
//    without the fence the consume VALU schedules above the wait).
//  - odd-gx loads: branch replaced by cndmask'd voffset (even lanes read
//    byte 0 of the level table — one shared extra line per wave, discarded).
//  - __launch_bounds__(256,8): 64-VGPR cap, 8 waves/SIMD kept. Est ~54 VGPR.
// Tell: VGPR_Count 48-64. H1 => enc ~220-290us. H2 => enc unchanged.
// Structure otherwise identical to R7 (3-pass; per-level dispatch is
// load-bearing for per-XCD L2 table locality — R4 proved fusion = 9x FETCH).

static constexpr uint32_t P1 = 2654435761u;
static constexpr uint32_t P2 = 805459861u;
static constexpr uint32_t NPARAMS = 7114752u;
static constexpr uint32_t HMASK = 524287u;

typedef float f32x4 __attribute__((ext_vector_type(4)));
typedef float f32x2 __attribute__((ext_vector_type(2)));

// ---------- asm gather primitives ----------
__device__ __forceinline__ unsigned long long gload2(
    uint32_t voff_bytes, const uint32_t* __restrict__ sbase)
{
    unsigned long long r;
    asm volatile("global_load_dwordx2 %0, %1, %2"
                 : "=v"(r) : "v"(voff_bytes), "s"(sbase));
    return r;
}
__device__ __forceinline__ uint32_t gload1(
    uint32_t voff_bytes, const uint32_t* __restrict__ sbase)
{
    uint32_t r;
    asm volatile("global_load_dword %0, %1, %2"
                 : "=v"(r) : "v"(voff_bytes), "s"(sbase));
    return r;
}

// ---------- pass 0 ----------
__device__ inline uint32_t bf16_bits(float f) {
    uint32_t u = __float_as_uint(f);
    return (u + 0x7FFFu + ((u >> 16) & 1u)) >> 16;
}

__global__ __launch_bounds__(256) void convert_bf16(
    const float* __restrict__ emb, uint32_t* __restrict__ tab)
{
    const uint32_t i = blockIdx.x * 256u + threadIdx.x;   // float4 index
    const float4 v = ((const float4*)emb)[i];
    uint2 o;
    o.x = bf16_bits(v.x) | (bf16_bits(v.y) << 16);
    o.y = bf16_bits(v.z) | (bf16_bits(v.w) << 16);
    ((uint2*)tab)[i] = o;
}

// ---------- pass 1: 2 points x 1 level per thread, forced 16-deep MLP ----------
__global__ __launch_bounds__(256, 8) void enc_level2(
    const float* __restrict__ inp,
    const uint32_t* __restrict__ tab,   // packed bf16x2 per row
    float2* __restrict__ stage,         // [16][np]
    int npoints)
{
    const uint32_t l = blockIdx.y;
    const uint32_t u = blockIdx.x * 256u + threadIdx.x;   // point-pair index

    // input: 3x float2 covering points 2u, 2u+1 (24B, 8B-aligned)
    const float2* in2 = (const float2*)inp;
    const float2 ab = in2[3u * u + 0u];   // x0 y0
    const float2 cd = in2[3u * u + 1u];   // z0 x1
    const float2 ef = in2[3u * u + 2u];   // y1 z1

    const uint32_t res = 16u << l;
    const float scale = (float)(res - 1u);

    uint32_t off;
    if (l >= 3u)      off = 299008u + (l - 3u) * 524288u;
    else if (l == 2u) off = 36864u;
    else if (l == 1u) off = 4096u;
    else              off = 0u;
    const bool hashed = (l >= 3u);
    const uint32_t s = 4u + (hashed ? 0u : l);
    const uint32_t* tabl = tab + off;     // block-uniform => SGPR pair

    const float xs[2] = {ab.x, cd.y};
    const float ys[2] = {ab.y, ef.x};
    const float zs[2] = {cd.x, ef.y};

    float    fxq[2], fyq[2], fzq[2];
    uint32_t meta[2];        // bits0-3: idxA[c]&1, bit4: gx odd
    uint32_t voA[2][4];      // byte offsets of aligned pairs
    uint32_t voB[2][4];      // byte offsets of odd-x corner (or 0 if even)

    // ---- address phase (pure VALU) ----
#pragma unroll
    for (int q = 0; q < 2; ++q) {
        const float posx = (xs[q] + 1.0f) * 0.5f * scale + 0.5f;
        const float posy = (ys[q] + 1.0f) * 0.5f * scale + 0.5f;
        const float posz = (zs[q] + 1.0f) * 0.5f * scale + 0.5f;
        const float fgx = floorf(posx), fgy = floorf(posy), fgz = floorf(posz);
        fxq[q] = posx - fgx; fyq[q] = posy - fgy; fzq[q] = posz - fgz;
        const uint32_t gx = (uint32_t)fgx, gy = (uint32_t)fgy, gz = (uint32_t)fgz;

        uint32_t yzc[4];
        if (hashed) {
            const uint32_t hy0 = gy * P1, hy1 = hy0 + P1;
            const uint32_t hz0 = gz * P2, hz1 = hz0 + P2;
            yzc[0] = hy0 ^ hz0; yzc[1] = hy1 ^ hz0;
            yzc[2] = hy0 ^ hz1; yzc[3] = hy1 ^ hz1;
        } else {
            const uint32_t dy0 = gy << s, dy1 = dy0 + (1u << s);
            const uint32_t dz0 = gz << (2u * s), dz1 = dz0 + (1u << (2u * s));
            yzc[0] = dy0 + dz0; yzc[1] = dy1 + dz0;
            yzc[2] = dy0 + dz1; yzc[3] = dy1 + dz1;
        }

        const bool odd = (gx & 1u) != 0u;
        uint32_t m = (gx & 1u) << 4;
#pragma unroll
        for (int c = 0; c < 4; ++c) {
            const uint32_t ia = hashed ? ((gx ^ yzc[c]) & HMASK) : (gx + yzc[c]);
            const uint32_t ib = hashed ? (((gx + 1u) ^ yzc[c]) & HMASK) : (ia + 1u);
            m |= (ia & 1u) << c;
            voA[q][c] = (ia & ~1u) * 4u;
            voB[q][c] = odd ? ib * 4u : 0u;   // even lanes: shared dummy line
        }
        meta[q] = m;
    }

    // ---- issue phase: 16 gathers back-to-back (asm-pinned) ----
    unsigned long long pr[2][4];
    uint32_t vBo[2][4];
#pragma unroll
    for (int q = 0; q < 2; ++q)
#pragma unroll
        for (int c = 0; c < 4; ++c)
            pr[q][c] = gload2(voA[q][c], tabl);
#pragma unroll
    for (int q = 0; q < 2; ++q)
#pragma unroll
        for (int c = 0; c < 4; ++c)
            vBo[q][c] = gload1(voB[q][c], tabl);

    // single drain; fence so consume VALU can't be scheduled above it
    asm volatile("s_waitcnt vmcnt(0)");
    __builtin_amdgcn_sched_barrier(0);

    // ---- consume phase ----
    f32x4 r;
#pragma unroll
    for (int q = 0; q < 2; ++q) {
        const float wx0 = 1.0f - fxq[q], wx1 = fxq[q];
        const float wy[2] = {1.0f - fyq[q], fyq[q]};
        const float wz[2] = {1.0f - fzq[q], fzq[q]};
        const bool odd = (meta[q] & 16u) != 0u;
        float sx = 0.0f, sy = 0.0f;
#pragma unroll
        for (int c = 0; c < 4; ++c) {
            const uint32_t plo = (uint32_t)pr[q][c];
            const uint32_t phi = (uint32_t)(pr[q][c] >> 32);
            const uint32_t lo = (meta[q] >> c) & 1u;
            const uint32_t vA  = lo ? phi : plo;
            const uint32_t vBe = lo ? plo : phi;   // idxA^1, valid iff gx even
            const uint32_t vB  = odd ? vBo[q][c] : vBe;
            const float wyz = wy[c & 1] * wz[c >> 1];
            const float eAx = __uint_as_float(vA << 16);
            const float eAy = __uint_as_float(vA & 0xFFFF0000u);
            const float eBx = __uint_as_float(vB << 16);
            const float eBy = __uint_as_float(vB & 0xFFFF0000u);
            sx = fmaf(wyz, fmaf(wx0, eAx, wx1 * eBx), sx);
            sy = fmaf(wyz, fmaf(wx0, eAy, wx1 * eBy), sy);
        }
        r[2 * q + 0] = sx;
        r[2 * q + 1] = sy;
    }

    // one nt float4 store: stage[l][2u .. 2u+1] (streaming; don't evict table)
    __builtin_nontemporal_store(r,
        (f32x4*)&((float4*)stage)[(size_t)l * ((uint32_t)npoints >> 1) + u]);
}

// ---------- pass 2: LDS-tiled transpose ----------
__global__ __launch_bounds__(256) void transpose_out(
    const float2* __restrict__ stage, float4* __restrict__ out4, int npoints)
{
    __shared__ float2 t[256][17];   // +1 pad: 2 lanes/bank on load phase (free)
    const uint32_t p0 = blockIdx.x * 256u;
    const uint32_t tid = threadIdx.x;

#pragma unroll
    for (int l = 0; l < 16; ++l) {
        const f32x2 v = __builtin_nontemporal_load(
            (const f32x2*)&stage[(size_t)l * (uint32_t)npoints + p0 + tid]);  // coalesced 2KB
        t[tid][l] = make_float2(v.x, v.y);
    }
    __syncthreads();

#pragma unroll
    for (int k = 0; k < 8; ++k) {
        const uint32_t f = (uint32_t)k * 256u + tid;
        const uint32_t p = f >> 3, c = f & 7u;
        const float2 a = t[p][2u * c];
        const float2 b = t[p][2u * c + 1u];
        const f32x4 v = {a.x, a.y, b.x, b.y};
        __builtin_nontemporal_store(v,
            (f32x4*)&out4[(size_t)(p0 + p) * 8u + c]);                        // coalesced 4KB
    }
}

// ---------- fallback: single-pass (R1) ----------
__global__ __launch_bounds__(256) void hashenc_fwd(
    const float* __restrict__ inp, const float* __restrict__ emb,
    float* __restrict__ out, int npoints)
{
    const uint32_t tid = blockIdx.x * 256u + threadIdx.x;
    const uint32_t p = tid >> 4, l = tid & 15u;
    if (p >= (uint32_t)npoints) return;
    const float x01 = (inp[p * 3u + 0u] + 1.0f) * 0.5f;
    const float y01 = (inp[p * 3u + 1u] + 1.0f) * 0.5f;
    const float z01 = (inp[p * 3u + 2u] + 1.0f) * 0.5f;
    const uint32_t res = 16u << l;
    const float scale = (float)(res - 1u);
    const float posx = x01 * scale + 0.5f, posy = y01 * scale + 0.5f, posz = z01 * scale + 0.5f;
    const float fgx = floorf(posx), fgy = floorf(posy), fgz = floorf(posz);
    const float fx = posx - fgx, fy = posy - fgy, fz = posz - fgz;
    const uint32_t gx = (uint32_t)fgx, gy = (uint32_t)fgy, gz = (uint32_t)fgz;
    uint32_t off;
    if (l >= 3u)      off = 299008u + (l - 3u) * 524288u;
    else if (l == 2u) off = 36864u;
    else if (l == 1u) off = 4096u;
    else              off = 0u;
    const bool hashed = (l >= 3u);
    const uint32_t s = 4u + (hashed ? 0u : l);
    const float wx[2] = {1.0f - fx, fx}, wy[2] = {1.0f - fy, fy}, wz[2] = {1.0f - fz, fz};
    float2 g[8]; float w[8];
#pragma unroll
    for (int c = 0; c < 8; ++c) {
        const uint32_t bx = (uint32_t)c & 1u, by = ((uint32_t)c >> 1) & 1u, bz = ((uint32_t)c >> 2) & 1u;
        const uint32_t cx = gx + bx, cy = gy + by, cz = gz + bz;
        const uint32_t hidx = (cx ^ (cy * P1) ^ (cz * P2)) & HMASK;
        const uint32_t didx = cx + (cy << s) + (cz << (2u * s));
        const uint32_t idx  = hashed ? hidx : didx;
        w[c] = wx[bx] * wy[by] * wz[bz];
        g[c] = *(const float2*)(emb + 2u * (off + idx));
    }
    float sx = 0.0f, sy = 0.0f;
#pragma unroll
    for (int c = 0; c < 8; ++c) { sx = fmaf(w[c], g[c].x, sx); sy = fmaf(w[c], g[c].y, sy); }
    *(float2*)(out + (size_t)p * 32u + (size_t)l * 2u) = make_float2(sx, sy);
}

extern "C" void kernel_launch(void* const* d_in, const int* in_sizes, int n_in,
                              void* d_out, int out_size, void* d_ws, size_t ws_size,
                              hipStream_t stream) {
    const float* inp = (const float*)d_in[0];
    const float* emb = (const float*)d_in[1];
    float* out = (float*)d_out;
    const int npoints = in_sizes[0] / 3;

    const size_t tab_bytes = (size_t)NPARAMS * 4u;
    const size_t stage_bytes = (size_t)npoints * 16u * 8u;
    const size_t need = tab_bytes + stage_bytes;

    if (ws_size >= need && (npoints & 511) == 0) {
        uint32_t* tab = (uint32_t*)d_ws;
        float2* stage = (float2*)((char*)d_ws + tab_bytes);

        const int conv_units = (int)(NPARAMS * 2u / 4u);
        convert_bf16<<<(conv_units + 255) / 256, 256, 0, stream>>>(emb, tab);

        dim3 g1(npoints / 512, 16);
        enc_level2<<<g1, 256, 0, stream>>>(inp, tab, stage, npoints);

        transpose_out<<<npoints / 256, 256, 0, stream>>>(stage, (float4*)out, npoints);
    } else {
        const int total = npoints * 16;
        hashenc_fwd<<<(total + 255) / 256, 256, 0, stream>>>(inp, emb, out, npoints);
    }
}